// Round 15
// baseline (67.916 us; speedup 1.0000x reference)
//
#include <hip/hip_runtime.h>
#include <math.h>

#define M_BATCH 8
#define NC 1024
#define NTGT 512
#define G_DIM 129
#define NG (G_DIM * G_DIM)        // 16641
#define N_OUT (G_DIM * 3)         // 387
#define TM 32                     // ix per block
#define TIY 32                    // iy per block
#define KCH 128
#define NKCH (NC / KCH)           // 8
#define LDA 136                   // padded LDS row stride (halves)
#define ABYTES (TM * LDA * 2)     // 8704 B per plane
#define BUFBYTES (2 * ABYTES)     // A + Wy = 17408 B per buffer
#define TBL_BYTES 4096            // ye (2KB) + yo (2KB)
#define SM8_OFF (TBL_BYTES + 2 * BUFBYTES)   // 38912
#define GT 5                      // tiles per dim

typedef __attribute__((ext_vector_type(8))) _Float16 half8;
typedef __attribute__((ext_vector_type(2))) _Float16 half2v;
typedef __attribute__((ext_vector_type(4))) float floatx4;

#if defined(__has_builtin)
#if __has_builtin(__builtin_amdgcn_exp2f)
#define FAST_EXP2(x) __builtin_amdgcn_exp2f(x)
#endif
#endif
#ifndef FAST_EXP2
#define FAST_EXP2(x) exp2f(x)
#endif

// Block = 32ix x 32iy x 3ch of batch m. 512 threads = 8 waves =
// 2x2 spatial subtiles x 2 K-groups. ye/yo live in a persistent 4KB LDS
// table built once (yc load overlapped with minmax); K-loop stages only
// A=wx and Wy (xc is L2-hot from minmax). Double-buffered, 1 barrier/chunk.
__global__ __launch_bounds__(512) void fused_kernel(
        const float* __restrict__ xc, const float* __restrict__ yc,
        const float* __restrict__ xt, const float* __restrict__ lsp,
        float* __restrict__ out_grid, float* __restrict__ out_z) {
    const int tid = threadIdx.x;
    const int iyt = blockIdx.x;        // 0..4
    const int mt = blockIdx.y;         // 0..4
    const int m  = blockIdx.z;

    // [ye 2048 | yo 2048 | buf0 17408 | buf1 17408 | sm8 128] = 39040 B
    __shared__ __align__(16) char lds_raw[SM8_OFF + 128];

    const int lane = tid & 63;
    const int w = tid >> 6;

    // ---- issue yc load early (cold miss overlaps minmax) ----
    const float4 yq_mine = ((const float4*)(yc + m * NC * 2))[tid];  // ctx pair 2*tid, 2*tid+1

    // ---- Phase 1: minmax over concat(xc[m], xt[m]), shuffle butterfly ----
    float mn0 = 1e30f, mx0 = -1e30f, mn1 = 1e30f, mx1 = -1e30f;
    {
        const float2* pc = (const float2*)(xc + m * NC * 2);
        for (int i = tid; i < NC; i += 512) {
            float2 p = pc[i];
            mn0 = fminf(mn0, p.x); mx0 = fmaxf(mx0, p.x);
            mn1 = fminf(mn1, p.y); mx1 = fmaxf(mx1, p.y);
        }
        const float2* pt = (const float2*)(xt + m * NTGT * 2);
        float2 p = pt[tid];
        mn0 = fminf(mn0, p.x); mx0 = fmaxf(mx0, p.x);
        mn1 = fminf(mn1, p.y); mx1 = fmaxf(mx1, p.y);
#pragma unroll
        for (int off = 32; off > 0; off >>= 1) {
            mn0 = fminf(mn0, __shfl_xor(mn0, off));
            mx0 = fmaxf(mx0, __shfl_xor(mx0, off));
            mn1 = fminf(mn1, __shfl_xor(mn1, off));
            mx1 = fmaxf(mx1, __shfl_xor(mx1, off));
        }
    }
    float4* sm8 = (float4*)(lds_raw + SM8_OFF);
    if (lane == 0) sm8[w] = make_float4(mn0, mx0, mn1, mx1);

    // ---- build ye/yo tables from the early yc load ----
    {
        _Float16* yeb = (_Float16*)lds_raw;
        _Float16* yob = (_Float16*)(lds_raw + 2048);
        *(half2v*)&yeb[2 * tid] = (half2v){(_Float16)yq_mine.x, (_Float16)yq_mine.z};
        *(half2v*)&yob[2 * tid] = (half2v){(_Float16)yq_mine.y, (_Float16)yq_mine.w};
    }
    __syncthreads();
    {
        float4 r = sm8[0];
#pragma unroll
        for (int i = 1; i < 8; ++i) {
            float4 b = sm8[i];
            r.x = fminf(r.x, b.x); r.y = fmaxf(r.y, b.y);
            r.z = fminf(r.z, b.z); r.w = fmaxf(r.w, b.w);
        }
        mn0 = r.x; mx0 = r.y; mn1 = r.z; mx1 = r.w;
    }
    const float mid0 = 0.5f * (mn0 + mx0);
    const float mid1 = 0.5f * (mn1 + mx1);

    const float Kc = 0.84932180028801904272f;  // sqrt(0.5*log2(e))
    const float ls0 = 1e-5f + log1pf(expf(lsp[0]));
    const float ls1 = 1e-5f + log1pf(expf(lsp[1]));
    const float s0 = Kc / ls0, s1 = Kc / ls1;
    const float inv_ppu = 1.0f / 64.0f;

    // ---- Phase 2: x_grid rows of this mt (iyt==0 blocks) ----
    if (iyt == 0) {
        const int r0 = mt * TM;
        const int nrows = min(TM, G_DIM - r0);
        float2* og = (float2*)out_grid + (size_t)m * NG;
        for (int g = tid; g < nrows * G_DIM; g += 512) {
            const int r = g / G_DIM;
            const int iyy = g - r * G_DIM;
            const int ixg = r0 + r;
            og[(size_t)ixg * G_DIM + iyy] =
                make_float2(mid0 + (float)(ixg - 64) * inv_ppu,
                            mid1 + (float)(iyy - 64) * inv_ppu);
        }
    }

    // ---- staging setup ----
    const int c2 = (tid & 63) * 2;        // local c pair
    const int r0s = tid >> 6;             // row slot base (rows r0s+8i)
    const float4* xc4 = (const float4*)(xc + m * NC * 2);
    const float gxs_base = (mid0 + (float)(mt * TM - 64) * inv_ppu) * s0;
    const float gys_base = (mid1 + (float)(iyt * TIY - 64) * inv_ppu) * s1;
    const float gstep_x = inv_ppu * s0;
    const float gstep_y = inv_ppu * s1;

    // ---- wave mapping: 8 waves = (g, wm, wn) ----
    const int g = w >> 2;                 // K-group 0/1
    const int wm = (w >> 1) & 1;
    const int wn = w & 1;
    const int ln = lane & 15;
    const int q = lane >> 4;

    floatx4 acc0 = {0.f, 0.f, 0.f, 0.f};
    floatx4 acc1 = {0.f, 0.f, 0.f, 0.f};
    floatx4 acc2 = {0.f, 0.f, 0.f, 0.f};

    auto stage = [&](int kc, int buf) {
        const int cp = kc * 64 + (tid & 63);
        const float4 xq = xc4[cp];
        const float cx0 = xq.x * s0, cx1 = xq.z * s0;
        const float cy0 = xq.y * s1, cy1 = xq.w * s1;
        _Float16* Ab  = (_Float16*)(lds_raw + TBL_BYTES + buf * BUFBYTES);
        _Float16* Wyb = (_Float16*)(lds_raw + TBL_BYTES + buf * BUFBYTES + ABYTES);
#pragma unroll
        for (int i = 0; i < 4; ++i) {
            const int r = r0s + 8 * i;
            const float gxs = gxs_base + (float)r * gstep_x;
            const float dx0 = gxs - cx0;
            const float dx1 = gxs - cx1;
            *(half2v*)&Ab[r * LDA + c2] =
                (half2v){(_Float16)FAST_EXP2(-(dx0 * dx0)),
                         (_Float16)FAST_EXP2(-(dx1 * dx1))};
            const float gys = gys_base + (float)r * gstep_y;
            const float dy0 = gys - cy0;
            const float dy1 = gys - cy1;
            *(half2v*)&Wyb[r * LDA + c2] =
                (half2v){(_Float16)FAST_EXP2(-(dy0 * dy0)),
                         (_Float16)FAST_EXP2(-(dy1 * dy1))};
        }
    };

    stage(0, 0);
    __syncthreads();

    const _Float16* yeb = (const _Float16*)lds_raw;
    for (int kc = 0; kc < NKCH; ++kc) {
        const int buf = kc & 1;
        const _Float16* Ab  = (const _Float16*)(lds_raw + TBL_BYTES + buf * BUFBYTES);
        const _Float16* Wyb = (const _Float16*)(lds_raw + TBL_BYTES + buf * BUFBYTES + ABYTES);
#pragma unroll
        for (int kk = 0; kk < 2; ++kk) {
            const int off = g * 64 + kk * 32 + q * 8;
            half8 a  = *(const half8*)&Ab[(wm * 16 + ln) * LDA + off];
            half8 wy = *(const half8*)&Wyb[(wn * 16 + ln) * LDA + off];
            half8 ye = *(const half8*)&yeb[kc * KCH + off];
            half8 yo = *(const half8*)&yeb[1024 + kc * KCH + off];
            acc2 = __builtin_amdgcn_mfma_f32_16x16x32_f16(a, wy, acc2, 0, 0, 0);
            acc0 = __builtin_amdgcn_mfma_f32_16x16x32_f16(a, wy * ye, acc0, 0, 0, 0);
            acc1 = __builtin_amdgcn_mfma_f32_16x16x32_f16(a, wy * yo, acc1, 0, 0, 0);
        }
        if (kc + 1 < NKCH) stage(kc + 1, buf ^ 1);
        __syncthreads();
    }

    // ---- cross-Kgroup reduction: g==1 writes, g==0 adds + stores ----
    floatx4* cs = (floatx4*)(lds_raw + TBL_BYTES);   // 12 KB, aliases buffers
    const int ws = wm * 2 + wn;
    if (g == 1) {
        cs[(ws * 3 + 0) * 64 + lane] = acc0;
        cs[(ws * 3 + 1) * 64 + lane] = acc1;
        cs[(ws * 3 + 2) * 64 + lane] = acc2;
    }
    __syncthreads();
    if (g == 0) {
        const floatx4 o0 = cs[(ws * 3 + 0) * 64 + lane];
        const floatx4 o1 = cs[(ws * 3 + 1) * 64 + lane];
        const floatx4 o2 = cs[(ws * 3 + 2) * 64 + lane];
        const int iyg = iyt * TIY + wn * 16 + ln;
        if (iyg < G_DIM) {
            float* oz = out_z + (size_t)m * NG * 3 + (size_t)iyg * 3;
            const int ixb = mt * TM + wm * 16 + q * 4;
#pragma unroll
            for (int rr = 0; rr < 4; ++rr) {
                const int ixg = ixb + rr;
                if (ixg < G_DIM) {
                    float* p = oz + (size_t)ixg * N_OUT;
                    p[0] = acc0[rr] + o0[rr];
                    p[1] = acc1[rr] + o1[rr];
                    p[2] = acc2[rr] + o2[rr];
                }
            }
        }
    }
}

extern "C" void kernel_launch(void* const* d_in, const int* in_sizes, int n_in,
                              void* d_out, int out_size, void* d_ws, size_t ws_size,
                              hipStream_t stream) {
    const float* xc  = (const float*)d_in[0];
    const float* yc  = (const float*)d_in[1];
    const float* xt  = (const float*)d_in[2];
    const float* lsp = (const float*)d_in[3];

    float* out_grid = (float*)d_out;
    float* out_z = out_grid + (size_t)M_BATCH * NG * 2;

    dim3 grid(GT, GT, M_BATCH);   // (5, 5, 8) = 200 blocks x 512 threads
    fused_kernel<<<grid, 512, 0, stream>>>(xc, yc, xt, lsp, out_grid, out_z);
}